// Round 1
// baseline (837.238 us; speedup 1.0000x reference)
//
#include <hip/hip_runtime.h>
#include <math.h>

// ---------------------------------------------------------------------------
// GaussianQuant: z[4,512,512] fp32, noise[2048,256] (unused in forward value),
// codebook[16384,32] fp32.
// Outputs (flat in d_out, all as fp32 per harness contract):
//   out0: zhat   [4,512,256] = 524288   (== zhat_v, gathered codebook rows)
//   out1: kl_loss scalar     = 1
//   out2: indices [4,512,8]  = 16384    (argmax index, stored as float)
//
// Score reformulation (row-constants dropped; preserves argmax):
//   score[n,k] = sum_d  p[n,d]*c[k,d] + q[n,d]*c[k,d]^2
//   p = mu*inv_var,  q = 0.5*(1 - inv_var),  inv_var = 1/(exp(0.5*lv))^2
// ---------------------------------------------------------------------------

#define DIM 32
#define CBN 8           // codebook_num
#define NTOK 2048
#define NROWS 16384     // NTOK * CBN
#define KSIZE 16384
#define WAVES_PB 8      // 512 threads / block
#define ROWS_PB 64
#define KCHUNK (KSIZE / WAVES_PB)   // 2048

// ws layout: [0,2048) = 256 doubles (kl partials); [2048, 2048+64KB) = int idx[16384]

__global__ __launch_bounds__(256) void kl_kernel(const float* __restrict__ z,
                                                 double* __restrict__ partials) {
  const int tid = threadIdx.x;
  const int lane = tid & 63;
  const int wave = tid >> 6;
  double s = 0.0;
  for (int j = blockIdx.x * 256 + tid; j < NTOK * 256; j += 256 * 256) {
    const int t = j >> 8, r = j & 255;
    float mu = z[t * 512 + r];
    float lv = z[t * 512 + 256 + r];
    lv = fminf(fmaxf(lv, -30.0f), 20.0f);
    float var = expf(lv);
    float term = mu * mu + var - 1.0f - lv;   // scale applied at the end
    s += (double)term;
  }
  // wave reduce
  for (int off = 32; off > 0; off >>= 1) s += __shfl_down(s, off);
  __shared__ double wsum[4];
  if (lane == 0) wsum[wave] = s;
  __syncthreads();
  if (tid == 0) partials[blockIdx.x] = (wsum[0] + wsum[1]) + (wsum[2] + wsum[3]);
}

__global__ __launch_bounds__(512) void search_kernel(const float* __restrict__ z,
                                                     const float* __restrict__ cb,
                                                     int* __restrict__ out_idx) {
  __shared__ float sbest[WAVES_PB][ROWS_PB];
  __shared__ int   sidx[WAVES_PB][ROWS_PB];

  const int lane = threadIdx.x & 63;
  // force wave-uniformity so codebook addresses become scalar/uniform loads
  const int wave = __builtin_amdgcn_readfirstlane(threadIdx.x >> 6);
  const int row  = blockIdx.x * ROWS_PB + lane;   // n in [0, 16384)
  const int t = row >> 3;
  const int c = row & 7;

  // per-row p,q in registers (64 VGPRs)
  float p[DIM], q[DIM];
#pragma unroll
  for (int d = 0; d < DIM; ++d) {
    float mu = z[t * 512 + d * 8 + c];
    float lv = z[t * 512 + 256 + d * 8 + c];
    lv = fminf(fmaxf(lv, -30.0f), 20.0f);
    float stdv = expf(0.5f * lv);
    float iv = 1.0f / (stdv * stdv);       // mimic reference 1/(std*std)
    p[d] = mu * iv;
    q[d] = 0.5f * (1.0f - iv);
  }

  float best = -INFINITY;
  int bidx = 0;
  const float4* __restrict__ cb4 = (const float4*)cb;
  const int k0 = wave * KCHUNK;

  for (int k = k0; k < k0 + KCHUNK; ++k) {
    float s0 = 0.0f, s1 = 0.0f, s2 = 0.0f, s3 = 0.0f;
#pragma unroll
    for (int m = 0; m < 8; ++m) {
      const float4 cv = cb4[k * 8 + m];
      const int d = 4 * m;
      s0 = fmaf(cv.x, fmaf(q[d + 0], cv.x, p[d + 0]), s0);
      s1 = fmaf(cv.y, fmaf(q[d + 1], cv.y, p[d + 1]), s1);
      s2 = fmaf(cv.z, fmaf(q[d + 2], cv.z, p[d + 2]), s2);
      s3 = fmaf(cv.w, fmaf(q[d + 3], cv.w, p[d + 3]), s3);
    }
    const float s = (s0 + s1) + (s2 + s3);
    if (s > best) { best = s; bidx = k; }   // strict > : first max within chunk
  }

  sbest[wave][lane] = best;
  sidx[wave][lane] = bidx;
  __syncthreads();

  if (wave == 0) {
    float b = sbest[0][lane];
    int bi = sidx[0][lane];
#pragma unroll
    for (int w = 1; w < WAVES_PB; ++w) {
      const float v = sbest[w][lane];
      if (v > b) { b = v; bi = sidx[w][lane]; }  // ascending chunks: ties keep lowest k
    }
    out_idx[row] = bi;
  }
}

__global__ __launch_bounds__(256) void finalize_kernel(const float* __restrict__ cb,
                                                       const int* __restrict__ idxarr,
                                                       const double* __restrict__ partials,
                                                       float* __restrict__ out0,
                                                       float* __restrict__ out1,
                                                       float* __restrict__ out2) {
  const int j = blockIdx.x * 256 + threadIdx.x;  // [0, 524288)
  const int t = j >> 8, r = j & 255;
  const int d = r >> 3, c = r & 7;
  const int n = t * 8 + c;
  const int idx = idxarr[n];
  out0[j] = cb[idx * DIM + d];
  if (j < NROWS) out2[j] = (float)idxarr[j];
  if (j == 0) {
    double s = 0.0;
    for (int i = 0; i < 256; ++i) s += partials[i];
    out1[0] = (float)(s * (1.4426 * 0.5) / (double)NROWS);
  }
}

extern "C" void kernel_launch(void* const* d_in, const int* in_sizes, int n_in,
                              void* d_out, int out_size, void* d_ws, size_t ws_size,
                              hipStream_t stream) {
  const float* z  = (const float*)d_in[0];
  // d_in[1] = noise: unused (zhat_g cancels in the straight-through estimator)
  const float* cb = (const float*)d_in[2];

  double* partials = (double*)d_ws;
  int* idxarr = (int*)((char*)d_ws + 2048);

  float* out0 = (float*)d_out;            // 524288
  float* out1 = out0 + 524288;            // 1
  float* out2 = out1 + 1;                 // 16384

  kl_kernel<<<256, 256, 0, stream>>>(z, partials);
  search_kernel<<<KSIZE / ROWS_PB, WAVES_PB * 64, 0, stream>>>(z, cb, idxarr);
  finalize_kernel<<<(NTOK * 256) / 256, 256, 0, stream>>>(cb, idxarr, partials,
                                                          out0, out1, out2);
}

// Round 2
// 522.652 us; speedup vs baseline: 1.6019x; 1.6019x over previous
//
#include <hip/hip_runtime.h>
#include <math.h>

// ---------------------------------------------------------------------------
// GaussianQuant: z[4,512,512] fp32, noise (unused in forward value),
// codebook[16384,32] fp32.
// Outputs (flat in d_out, fp32): zhat[524288] (= gathered codebook rows),
// kl_loss[1], indices[16384] (as float).
//
// score[n,k] = sum_d p[n,d]*c[k,d] + q[n,d]*c[k,d]^2   (row-constants dropped)
//   p = mu*inv_var, q = 0.5*(1-inv_var), inv_var = 1/(exp(0.5*lv))^2
//
// R2: K split 16-ways (blockIdx.y) for occupancy; __launch_bounds__(256,4)
// to stop the R1 p/q scratch spill (VGPR was 40 < 64 needed).
// ---------------------------------------------------------------------------

#define DIM 32
#define NTOK 2048
#define NROWS 16384     // NTOK * 8
#define KSIZE 16384
#define KSPLIT 16
#define KCH (KSIZE / KSPLIT)   // 1024

// ws layout:
//   [0, 2048)                : 256 doubles  — kl partials
//   [4096, 4096+1MB)         : float pbest[KSPLIT][NROWS]
//   [4096+1MB, 4096+2MB)     : int   pidx [KSPLIT][NROWS]
//   [4096+2MB, 4096+2MB+64K) : int   idx_final[NROWS]

__global__ __launch_bounds__(256) void kl_kernel(const float* __restrict__ z,
                                                 double* __restrict__ partials) {
  const int tid = threadIdx.x;
  const int lane = tid & 63;
  const int wave = tid >> 6;
  double s = 0.0;
  for (int j = blockIdx.x * 256 + tid; j < NTOK * 256; j += 256 * 256) {
    const int t = j >> 8, r = j & 255;
    float mu = z[t * 512 + r];
    float lv = z[t * 512 + 256 + r];
    lv = fminf(fmaxf(lv, -30.0f), 20.0f);
    float var = expf(lv);
    s += (double)(mu * mu + var - 1.0f - lv);
  }
  for (int off = 32; off > 0; off >>= 1) s += __shfl_down(s, off);
  __shared__ double wsum[4];
  if (lane == 0) wsum[wave] = s;
  __syncthreads();
  if (tid == 0) partials[blockIdx.x] = (wsum[0] + wsum[1]) + (wsum[2] + wsum[3]);
}

__global__ __launch_bounds__(256, 4) void search_kernel(const float* __restrict__ z,
                                                        const float* __restrict__ cb,
                                                        float* __restrict__ pbest,
                                                        int* __restrict__ pidx) {
  const int row = blockIdx.x * 256 + threadIdx.x;   // [0, 16384)
  const int chunk = blockIdx.y;                     // [0, KSPLIT) — uniform
  const int t = row >> 3;
  const int c = row & 7;

  float p[DIM], q[DIM];
#pragma unroll
  for (int d = 0; d < DIM; ++d) {
    float mu = z[t * 512 + d * 8 + c];
    float lv = z[t * 512 + 256 + d * 8 + c];
    lv = fminf(fmaxf(lv, -30.0f), 20.0f);
    float stdv = expf(0.5f * lv);
    float iv = 1.0f / (stdv * stdv);      // mimic reference 1/(std*std)
    p[d] = mu * iv;
    q[d] = 0.5f * (1.0f - iv);
  }

  const int k0 = chunk * KCH;
  const float4* __restrict__ cb4 = (const float4*)cb + (size_t)k0 * 8;

  float best = -INFINITY;
  int bidx = 0;
#pragma unroll 2
  for (int k = 0; k < KCH; ++k) {
    float s0 = 0.0f, s1 = 0.0f, s2 = 0.0f, s3 = 0.0f;
#pragma unroll
    for (int m = 0; m < 8; ++m) {
      const float4 cv = cb4[k * 8 + m];   // address uniform across the wave
      const int d = 4 * m;
      s0 = fmaf(cv.x, fmaf(q[d + 0], cv.x, p[d + 0]), s0);
      s1 = fmaf(cv.y, fmaf(q[d + 1], cv.y, p[d + 1]), s1);
      s2 = fmaf(cv.z, fmaf(q[d + 2], cv.z, p[d + 2]), s2);
      s3 = fmaf(cv.w, fmaf(q[d + 3], cv.w, p[d + 3]), s3);
    }
    const float s = (s0 + s1) + (s2 + s3);
    if (s > best) { best = s; bidx = k; }  // strict >: first max within chunk
  }

  pbest[chunk * NROWS + row] = best;
  pidx[chunk * NROWS + row] = k0 + bidx;
}

__global__ __launch_bounds__(256) void merge_kernel(const float* __restrict__ pbest,
                                                    const int* __restrict__ pidx,
                                                    int* __restrict__ idx_final,
                                                    const double* __restrict__ partials,
                                                    float* __restrict__ out1,
                                                    float* __restrict__ out2) {
  const int row = blockIdx.x * 256 + threadIdx.x;   // [0, 16384)
  float b = pbest[row];
  int bi = pidx[row];
#pragma unroll
  for (int ch = 1; ch < KSPLIT; ++ch) {
    const float v = pbest[ch * NROWS + row];
    if (v > b) { b = v; bi = pidx[ch * NROWS + row]; }  // ascending: ties keep lowest k
  }
  idx_final[row] = bi;
  out2[row] = (float)bi;
  if (row == 0) {
    double s = 0.0;
    for (int i = 0; i < 256; ++i) s += partials[i];
    out1[0] = (float)(s * (1.4426 * 0.5) / (double)NROWS);
  }
}

__global__ __launch_bounds__(256) void gather_kernel(const float* __restrict__ cb,
                                                     const int* __restrict__ idx_final,
                                                     float* __restrict__ out0) {
  const int j = blockIdx.x * 256 + threadIdx.x;  // [0, 524288)
  const int t = j >> 8, r = j & 255;
  const int d = r >> 3, c = r & 7;
  const int n = t * 8 + c;
  out0[j] = cb[idx_final[n] * DIM + d];
}

extern "C" void kernel_launch(void* const* d_in, const int* in_sizes, int n_in,
                              void* d_out, int out_size, void* d_ws, size_t ws_size,
                              hipStream_t stream) {
  const float* z  = (const float*)d_in[0];
  const float* cb = (const float*)d_in[2];   // d_in[1]=noise unused (STE cancels)

  char* ws = (char*)d_ws;
  double* partials = (double*)ws;
  float* pbest     = (float*)(ws + 4096);
  int*   pidx      = (int*)(ws + 4096 + (size_t)KSPLIT * NROWS * 4);
  int*   idx_final = (int*)(ws + 4096 + (size_t)2 * KSPLIT * NROWS * 4);

  float* out0 = (float*)d_out;            // 524288
  float* out1 = out0 + 524288;            // 1
  float* out2 = out1 + 1;                 // 16384

  kl_kernel<<<256, 256, 0, stream>>>(z, partials);
  dim3 sgrid(NROWS / 256, KSPLIT);
  search_kernel<<<sgrid, 256, 0, stream>>>(z, cb, pbest, pidx);
  merge_kernel<<<NROWS / 256, 256, 0, stream>>>(pbest, pidx, idx_final,
                                                partials, out1, out2);
  gather_kernel<<<(NTOK * 256) / 256, 256, 0, stream>>>(cb, idx_final, out0);
}